// Round 17
// baseline (281.681 us; speedup 1.0000x reference)
//
#include <hip/hip_runtime.h>

#define IN_DIM 128
#define HID 64
#define NC 32
#define SCAN_TILE 2048   // 256 threads x 8

__device__ __forceinline__ unsigned short f2bf(float f) {
    unsigned b = __float_as_uint(f);
    unsigned r = (b + 0x7FFFu + ((b >> 16) & 1u)) >> 16;   // RNE
    return (unsigned short)r;
}
__device__ __forceinline__ float bf2f(unsigned short u) {
    return __uint_as_float(((unsigned)u) << 16);
}

// ---- histogram + rank: rank[e] = old count of dst ----
__global__ void hist_kernel(const int* __restrict__ dst, int* __restrict__ deg,
                            int* __restrict__ rank, int E) {
    int e = blockIdx.x * blockDim.x + threadIdx.x;
    if (e < E) rank[e] = atomicAdd(&deg[dst[e]], 1);
}

// ---- per-tile inclusive scan (2048 ints/block) ----
__global__ __launch_bounds__(256) void scan_tile_kernel(const int* __restrict__ in,
                                                        int* __restrict__ out,
                                                        int* __restrict__ partials, int n) {
    __shared__ int tsum[256];
    int t = threadIdx.x;
    int base = blockIdx.x * SCAN_TILE + t * 8;
    int v[8];
    int s = 0;
    #pragma unroll
    for (int j = 0; j < 8; ++j) {
        int idx = base + j;
        int x = (idx < n) ? in[idx] : 0;
        s += x;
        v[j] = s;
    }
    tsum[t] = s;
    __syncthreads();
    for (int off = 1; off < 256; off <<= 1) {
        int add = (t >= off) ? tsum[t - off] : 0;
        __syncthreads();
        tsum[t] += add;
        __syncthreads();
    }
    int excl = tsum[t] - s;
    #pragma unroll
    for (int j = 0; j < 8; ++j) {
        int idx = base + j;
        if (idx < n) out[idx] = v[j] + excl;
    }
    if (t == 255) partials[blockIdx.x] = tsum[255];
}

__global__ void scan_partials_kernel(int* __restrict__ partials, int nb) {
    if (threadIdx.x == 0 && blockIdx.x == 0) {
        int run = 0;
        for (int b = 0; b < nb; ++b) { int x = partials[b]; partials[b] = run; run += x; }
    }
}

// ---- rowptr + dinv fused (both n-sized elementwise) ----
__global__ void rowptr_dinv_kernel(const int* __restrict__ scan_buf, const int* __restrict__ partials,
                                   const int* __restrict__ deg, int* __restrict__ rowptr,
                                   float* __restrict__ dinv, int n) {
    int i = blockIdx.x * blockDim.x + threadIdx.x;
    if (i < n) {
        rowptr[i + 1] = scan_buf[i] + partials[i / SCAN_TILE];
        dinv[i] = rsqrtf((float)deg[i] + 1.0f);
    }
    if (i == 0) rowptr[0] = 0;
}

// ---- scatter (no atomics): e_src[rowptr[d]+rank[e]] = src ----
__global__ void scatter_kernel(const int* __restrict__ src, const int* __restrict__ dst,
                               const int* __restrict__ rank, const int* __restrict__ rowptr,
                               int* __restrict__ e_src, int E) {
    int e = blockIdx.x * blockDim.x + threadIdx.x;
    if (e >= E) return;
    int d = dst[e];
    e_src[rowptr[d] + rank[e]] = src[e];
}

// ---- hp0[n,64] = (x[n,128] @ W0[128,64]) * dinv[row], stored bf16 ----
__global__ __launch_bounds__(256) void gemm0_kernel(const float* __restrict__ x,
                                                    const float* __restrict__ W,
                                                    const float* __restrict__ dinv,
                                                    unsigned short* __restrict__ hp0, int n) {
    __shared__ float Ws[IN_DIM * HID];    // 32 KiB
    __shared__ float xs[16][IN_DIM];      // 8 KiB
    int tid = threadIdx.x;
    const float4* W4 = (const float4*)W;
    float4* Ws4 = (float4*)Ws;
    #pragma unroll
    for (int j = 0; j < 8; ++j) Ws4[tid + 256 * j] = W4[tid + 256 * j];
    int base = blockIdx.x * 16;
    const float4* x4 = (const float4*)(x + (size_t)base * IN_DIM);
    float4* xs4 = (float4*)xs;
    #pragma unroll
    for (int j = 0; j < 2; ++j) {
        int i = tid + 256 * j;
        if (base + (i >> 5) < n) xs4[i] = x4[i];
    }
    __syncthreads();
    int r = tid >> 4;
    int c4 = (tid & 15) * 4;
    int row = base + r;
    if (row >= n) return;
    float4 acc = make_float4(0.f, 0.f, 0.f, 0.f);
    #pragma unroll
    for (int k = 0; k < IN_DIM; ++k) {
        float xv = xs[r][k];
        float4 w = *(const float4*)&Ws[k * HID + c4];
        acc.x += xv * w.x; acc.y += xv * w.y; acc.z += xv * w.z; acc.w += xv * w.w;
    }
    float dv = dinv[row];
    ushort4 o;
    o.x = f2bf(acc.x * dv); o.y = f2bf(acc.y * dv);
    o.z = f2bf(acc.z * dv); o.w = f2bf(acc.w * dv);
    *(ushort4*)&hp0[(size_t)row * HID + c4] = o;
}

// ---- gather layer 1, column-half pass: one wave per node, 32 cols, 2 edges/wave ----
// L2-residency: the 32-col slice of hp0 is 3.2 MB < 4 MB per-XCD L2.
__global__ __launch_bounds__(256) void gather0_kernel(const int* __restrict__ rowptr,
                                                      const int* __restrict__ e_src,
                                                      const unsigned short* __restrict__ hp0,
                                                      const float* __restrict__ dinv,
                                                      const float* __restrict__ b0,
                                                      const float* __restrict__ mask,
                                                      unsigned short* __restrict__ hb,
                                                      int n, int colbase) {
    int v = blockIdx.x * 4 + (threadIdx.x >> 6);
    if (v >= n) return;
    int lane = threadIdx.x & 63;
    int half = lane >> 5;                 // even/odd edge stream
    int col = colbase + (lane & 31);
    int start = rowptr[v], end = rowptr[v + 1];
    float acc = 0.f;
    for (int p = start; p < end; p += 16) {
        int ss[8]; bool vv[8];
        #pragma unroll
        for (int i = 0; i < 8; ++i) {
            int q = p + 2 * i + half;
            vv[i] = q < end;
            ss[i] = e_src[vv[i] ? q : end - 1];
        }
        unsigned short gu[8];
        #pragma unroll
        for (int i = 0; i < 8; ++i) gu[i] = hp0[(size_t)ss[i] * HID + col];
        #pragma unroll
        for (int i = 0; i < 8; ++i) acc += vv[i] ? bf2f(gu[i]) : 0.f;
    }
    acc += __shfl(acc, lane ^ 32);        // combine even+odd streams
    if (half == 0) {
        float dv = dinv[v];
        float val = dv * (acc + bf2f(hp0[(size_t)v * HID + col])) + b0[col];
        val = val > 0.f ? val : 0.f;
        val = val * mask[(size_t)v * HID + col] * dv;
        hb[(size_t)v * HID + col] = f2bf(val);
    }
}

// ---- gather layer 2, column-half pass: T[v,col] = sum hb[src,col] + hb[v,col] ----
__global__ __launch_bounds__(256) void gather2_kernel(const int* __restrict__ rowptr,
                                                      const int* __restrict__ e_src,
                                                      const unsigned short* __restrict__ hb,
                                                      float* __restrict__ T, int n, int colbase) {
    int v = blockIdx.x * 4 + (threadIdx.x >> 6);
    if (v >= n) return;
    int lane = threadIdx.x & 63;
    int half = lane >> 5;
    int col = colbase + (lane & 31);
    int start = rowptr[v], end = rowptr[v + 1];
    float acc = 0.f;
    for (int p = start; p < end; p += 16) {
        int ss[8]; bool vv[8];
        #pragma unroll
        for (int i = 0; i < 8; ++i) {
            int q = p + 2 * i + half;
            vv[i] = q < end;
            ss[i] = e_src[vv[i] ? q : end - 1];
        }
        unsigned short gu[8];
        #pragma unroll
        for (int i = 0; i < 8; ++i) gu[i] = hb[(size_t)ss[i] * HID + col];
        #pragma unroll
        for (int i = 0; i < 8; ++i) acc += vv[i] ? bf2f(gu[i]) : 0.f;
    }
    acc += __shfl(acc, lane ^ 32);
    if (half == 0) {
        T[(size_t)v * HID + col] = acc + bf2f(hb[(size_t)v * HID + col]);   // self-loop
    }
}

// ---- fused final GEMM + reparameterize: S = dinv*T ; mu=S@W1+b1 ; lv=S@W2+b2 ; z=eps*exp(lv)+mu ----
__global__ __launch_bounds__(256) void gemm2_kernel(const float* __restrict__ T,
                                                    const float* __restrict__ dinv,
                                                    const float* __restrict__ W1,
                                                    const float* __restrict__ W2,
                                                    const float* __restrict__ b1,
                                                    const float* __restrict__ b2,
                                                    const float* __restrict__ eps,
                                                    float* __restrict__ zout,
                                                    float* __restrict__ muout,
                                                    float* __restrict__ lvout, int n) {
    __shared__ float W1s[HID * NC];
    __shared__ float W2s[HID * NC];
    __shared__ float Ss[16][HID];
    int tid = threadIdx.x;
    const float4* W14 = (const float4*)W1;
    const float4* W24 = (const float4*)W2;
    float4* W1s4 = (float4*)W1s;
    float4* W2s4 = (float4*)W2s;
    #pragma unroll
    for (int j = 0; j < 2; ++j) {
        W1s4[tid + 256 * j] = W14[tid + 256 * j];
        W2s4[tid + 256 * j] = W24[tid + 256 * j];
    }
    int base = blockIdx.x * 16;
    {
        int row = base + (tid >> 4);
        int cc = (tid & 15) * 4;
        if (row < n) {
            float dv = dinv[row];
            float4 tv = *(const float4*)&T[(size_t)row * HID + cc];
            float4 s;
            s.x = dv * tv.x; s.y = dv * tv.y; s.z = dv * tv.z; s.w = dv * tv.w;
            *(float4*)&Ss[tid >> 4][cc] = s;
        }
    }
    __syncthreads();
    int r = tid >> 4;
    int q = tid & 15;
    int head = q >> 3;
    int c4 = (q & 7) * 4;
    int row = base + r;
    if (row >= n) return;
    const float* Wp = head ? W2s : W1s;
    float4 acc = make_float4(0.f, 0.f, 0.f, 0.f);
    #pragma unroll
    for (int k = 0; k < HID; ++k) {
        float xv = Ss[r][k];
        float4 w = *(const float4*)&Wp[k * NC + c4];
        acc.x += xv * w.x; acc.y += xv * w.y; acc.z += xv * w.z; acc.w += xv * w.w;
    }
    const float* bb = head ? b2 : b1;
    acc.x += bb[c4]; acc.y += bb[c4 + 1]; acc.z += bb[c4 + 2]; acc.w += bb[c4 + 3];
    int lane = threadIdx.x & 63;
    float4 other;
    other.x = __shfl(acc.x, lane ^ 8);
    other.y = __shfl(acc.y, lane ^ 8);
    other.z = __shfl(acc.z, lane ^ 8);
    other.w = __shfl(acc.w, lane ^ 8);
    size_t o = (size_t)row * NC + c4;
    if (head == 0) {
        *(float4*)&muout[o] = acc;
        float4 ev = *(const float4*)&eps[o];
        float4 z;
        z.x = ev.x * expf(other.x) + acc.x;
        z.y = ev.y * expf(other.y) + acc.y;
        z.z = ev.z * expf(other.z) + acc.z;
        z.w = ev.w * expf(other.w) + acc.w;
        *(float4*)&zout[o] = z;
    } else {
        *(float4*)&lvout[o] = acc;
    }
}

extern "C" void kernel_launch(void* const* d_in, const int* in_sizes, int n_in,
                              void* d_out, int out_size, void* d_ws, size_t ws_size,
                              hipStream_t stream) {
    const float* x    = (const float*)d_in[0];
    const int*   ei   = (const int*)d_in[1];
    const float* W0   = (const float*)d_in[2];
    const float* b0   = (const float*)d_in[3];
    const float* W1   = (const float*)d_in[4];
    const float* b1   = (const float*)d_in[5];
    const float* W2   = (const float*)d_in[6];
    const float* b2   = (const float*)d_in[7];
    const float* mask = (const float*)d_in[8];
    const float* eps  = (const float*)d_in[9];

    int n = in_sizes[0] / IN_DIM;   // 50000
    int E = in_sizes[1] / 2;        // 800000
    const int* src = ei;
    const int* dst = ei + E;

    // workspace layout (4-byte units)
    int*   ws_i    = (int*)d_ws;
    int*   deg_i   = ws_i;                        // 50048
    int*   rowptr  = deg_i + 50048;               // 50056
    int*   scanbuf = rowptr + 50056;              // 50048
    int*   partials= scanbuf + 50048;             // 64
    float* dinv    = (float*)(partials + 64);     // 50048
    int*   rank    = (int*)(dinv + 50048);        // E
    int*   e_src   = rank + E;                    // E
    unsigned short* hp0 = (unsigned short*)(e_src + E);      // n*64 bf16
    unsigned short* hb  = hp0 + (size_t)n * HID;             // n*64 bf16
    float* T       = (float*)(hb + (size_t)n * HID);         // n*64 fp32

    float* zout  = (float*)d_out;                 // n*32
    float* muout = zout + (size_t)n * NC;
    float* lvout = muout + (size_t)n * NC;

    int nb = (n + SCAN_TILE - 1) / SCAN_TILE;     // 25
    int ngb = (n + 3) / 4;

    hipMemsetAsync(deg_i, 0, 50048 * sizeof(int), stream);

    hist_kernel<<<(E + 255) / 256, 256, 0, stream>>>(dst, deg_i, rank, E);
    scan_tile_kernel<<<nb, 256, 0, stream>>>(deg_i, scanbuf, partials, n);
    scan_partials_kernel<<<1, 64, 0, stream>>>(partials, nb);
    rowptr_dinv_kernel<<<(n + 255) / 256, 256, 0, stream>>>(scanbuf, partials, deg_i,
                                                            rowptr, dinv, n);
    gemm0_kernel<<<(n + 15) / 16, 256, 0, stream>>>(x, W0, dinv, hp0, n);
    scatter_kernel<<<(E + 255) / 256, 256, 0, stream>>>(src, dst, rank, rowptr, e_src, E);
    gather0_kernel<<<ngb, 256, 0, stream>>>(rowptr, e_src, hp0, dinv, b0, mask, hb, n, 0);
    gather0_kernel<<<ngb, 256, 0, stream>>>(rowptr, e_src, hp0, dinv, b0, mask, hb, n, 32);
    gather2_kernel<<<ngb, 256, 0, stream>>>(rowptr, e_src, hb, T, n, 0);
    gather2_kernel<<<ngb, 256, 0, stream>>>(rowptr, e_src, hb, T, n, 32);
    gemm2_kernel<<<(n + 15) / 16, 256, 0, stream>>>(T, dinv, W1, W2, b1, b2, eps,
                                                    zout, muout, lvout, n);
}